// Round 2
// baseline (46.239 us; speedup 1.0000x reference)
//
#include <hip/hip_runtime.h>

#define NPTS 512
#define DIM  128
#define MARGIN 0.5f
#define CNT_EPS 1e-8f
#define FIXSCALE 16777216.0   // 2^24 fixed-point scale for deterministic atomics

struct Accum {
    unsigned long long sum;    // fixed-point (2^24) total loss
    unsigned int       cnt;    // number of positives
    unsigned int       ticket; // arrival counter for last-block finalize
};

// ---------------------------------------------------------------------------
// One block per anchor i. Fully fused:
//   - load row i to LDS; wave 0 computes ||xi||^2
//   - for each j: float4 dot(i,j) AND ||xj||^2 in one pass -> distance
//   - compact positives (d_ij + margin) / negatives (d_ik) into LDS lists
//   - dense pos x neg pair loop -> block partial (sum, count)
//   - fixed-point device atomics; last block (ticket) writes out = sum/cnt
// ---------------------------------------------------------------------------
__global__ __launch_bounds__(256)
void triplet_fused_kernel(const float* __restrict__ x,
                          const int* __restrict__ labels,
                          float* __restrict__ out,
                          Accum* __restrict__ acc,
                          int nblocks) {
    __shared__ float xi[DIM];
    __shared__ float pos[NPTS];
    __shared__ float neg[NPTS];
    __shared__ int   cnts[2];        // [0]=npos, [1]=nneg
    __shared__ float sqi_sh;
    __shared__ float red_s[256];
    __shared__ int   red_c[256];

    const int i   = blockIdx.x;
    const int tid = threadIdx.x;

    if (tid < DIM) xi[tid] = x[i * DIM + tid];
    if (tid < 2)   cnts[tid] = 0;
    const int li = labels[i];
    __syncthreads();

    // wave 0: sqi = ||xi||^2 via shuffle reduce
    if (tid < 64) {
        float s = 0.f;
        for (int d = tid; d < DIM; d += 64) {
            float v = xi[d];
            s += v * v;
        }
        for (int off = 32; off > 0; off >>= 1)
            s += __shfl_down(s, off, 64);
        if (tid == 0) sqi_sh = s;
    }
    __syncthreads();
    const float sqi = sqi_sh;

    const float4* xi4 = (const float4*)xi;
    for (int j = tid; j < NPTS; j += 256) {
        const float4* xj4 = (const float4*)(x + j * DIM);
        float dot = 0.f;
        float sqj = 0.f;
#pragma unroll
        for (int q = 0; q < DIM / 4; ++q) {
            float4 a = xi4[q];
            float4 b = xj4[q];
            dot += a.x * b.x + a.y * b.y + a.z * b.z + a.w * b.w;
            sqj += b.x * b.x + b.y * b.y + b.z * b.z + b.w * b.w;
        }
        float dsq = sqi + sqj - 2.f * dot;
        dsq = dsq > 0.f ? dsq : 0.f;
        // reference's zero-mask path only affects exact-zero entries (the
        // diagonal), which validity excludes -> plain sqrt is exact here.
        float dist = (dsq == 0.f) ? 0.f : sqrtf(dsq);

        int lj = labels[j];
        if (lj == li) {
            if (j != i) {
                int p = atomicAdd(&cnts[0], 1);
                pos[p] = dist + MARGIN;
            }
        } else {
            int q = atomicAdd(&cnts[1], 1);
            neg[q] = dist;
        }
    }
    __syncthreads();

    const int npos = cnts[0];
    const int nneg = cnts[1];

    float lsum = 0.f;
    int   lcnt = 0;
    for (int p = 0; p < npos; ++p) {
        const float a = pos[p];
        for (int k = tid; k < nneg; k += 256) {
            float v = a - neg[k];            // d_ij - d_ik + margin
            if (v > 0.f) {
                lsum += v;
                lcnt += (v > CNT_EPS) ? 1 : 0;
            }
        }
    }

    red_s[tid] = lsum;
    red_c[tid] = lcnt;
    __syncthreads();
    for (int s = 128; s > 0; s >>= 1) {
        if (tid < s) {
            red_s[tid] += red_s[tid + s];
            red_c[tid] += red_c[tid + s];
        }
        __syncthreads();
    }

    if (tid == 0) {
        // deterministic fixed-point accumulation (fp32 block partial, fixed order)
        unsigned long long q =
            (unsigned long long)((double)red_s[0] * FIXSCALE + 0.5);
        atomicAdd(&acc->sum, q);
        atomicAdd(&acc->cnt, (unsigned int)red_c[0]);
        __threadfence();                      // publish before ticket
        unsigned int t = atomicAdd(&acc->ticket, 1u);
        if (t == (unsigned int)(nblocks - 1)) {
            // last arriver: totals are complete; read via device-scope atomics
            unsigned long long s = atomicAdd(&acc->sum, 0ULL);
            unsigned int       c = atomicAdd(&acc->cnt, 0u);
            out[0] = (float)(((double)s / FIXSCALE) / (double)c);
        }
    }
}

extern "C" void kernel_launch(void* const* d_in, const int* in_sizes, int n_in,
                              void* d_out, int out_size, void* d_ws, size_t ws_size,
                              hipStream_t stream) {
    const float* x      = (const float*)d_in[0];   // [512,128] fp32
    const int*   labels = (const int*)d_in[1];     // [512] int32
    float*       out    = (float*)d_out;           // scalar fp32
    Accum*       acc    = (Accum*)d_ws;

    hipMemsetAsync(acc, 0, sizeof(Accum), stream); // re-zero each call (replay-safe)
    triplet_fused_kernel<<<NPTS, 256, 0, stream>>>(x, labels, out, acc, NPTS);
}

// Round 3
// 37.079 us; speedup vs baseline: 1.2470x; 1.2470x over previous
//
#include <hip/hip_runtime.h>

#define NPTS 512
#define DIM  128
#define MARGIN 0.5f
#define CNT_EPS 1e-8f
#define FIXSCALE 16777216.0   // 2^24 fixed-point scale for deterministic atomics

struct Accum {
    unsigned long long sum;    // fixed-point (2^24) total loss
    unsigned int       cnt;    // number of positives
    unsigned int       ticket; // arrival counter for last-block finalize
};

__device__ __forceinline__ float dot4(float4 a, float4 b) {
    return a.x * b.x + a.y * b.y + a.z * b.z + a.w * b.w;
}

// ---------------------------------------------------------------------------
// One block (256 thr = 4 waves) per anchor i.
// Distance phase: 4 lanes per row j, 16 rows per wave per pass, 8 passes.
//   -> each wave-level load touches 16 fully-used 64B lines (coalesced),
//      anchor row xi held in registers (8 x float4 per lane).
// Then: full distance row in LDS, compact ~8 positives, predicated pair loop,
// block reduce, fixed-point device atomics, ticket'd last-block finalize.
// ---------------------------------------------------------------------------
__global__ __launch_bounds__(256)
void triplet_fused_kernel(const float* __restrict__ x,
                          const int* __restrict__ labels,
                          float* __restrict__ out,
                          Accum* __restrict__ acc,
                          int nblocks) {
    __shared__ float drow[NPTS];   // distance row d[i][*]
    __shared__ int   lab[NPTS];
    __shared__ float posv[NPTS];   // positive d+margin (robust size)
    __shared__ int   npos_sh;
    __shared__ float red_s[256];
    __shared__ int   red_c[256];

    const int i   = blockIdx.x;
    const int tid = threadIdx.x;
    const int w   = tid >> 6;      // wave 0..3
    const int l   = tid & 63;      // lane
    const int g   = l >> 2;        // row-group 0..15 within wave
    const int c   = l & 3;         // column slot 0..3 within group

    lab[tid]       = labels[tid];
    lab[tid + 256] = labels[tid + 256];
    if (tid == 0) npos_sh = 0;
    const int li = labels[i];

    // anchor row fragment in registers: columns c+4*it (it=0..7)
    const float4* xi4 = (const float4*)(x + i * DIM);
    float4 xf[8];
#pragma unroll
    for (int it = 0; it < 8; ++it) xf[it] = xi4[c + 4 * it];

    // sqi = ||xi||^2 : per-lane partial over its columns, 4-lane butterfly
    float sqi = 0.f;
#pragma unroll
    for (int it = 0; it < 8; ++it) sqi += dot4(xf[it], xf[it]);
    sqi += __shfl_xor(sqi, 1, 64);
    sqi += __shfl_xor(sqi, 2, 64);

    // distance rows: wave w, pass p covers rows p*64 + w*16 + g
#pragma unroll 2
    for (int pass = 0; pass < 8; ++pass) {
        const int j = pass * 64 + w * 16 + g;
        const float4* xj4 = (const float4*)(x + j * DIM);
        float dp = 0.f, sp = 0.f;
#pragma unroll
        for (int it = 0; it < 8; ++it) {
            float4 b = xj4[c + 4 * it];
            dp += dot4(b, xf[it]);
            sp += dot4(b, b);
        }
        dp += __shfl_xor(dp, 1, 64);
        dp += __shfl_xor(dp, 2, 64);
        sp += __shfl_xor(sp, 1, 64);
        sp += __shfl_xor(sp, 2, 64);
        if (c == 0) {
            float dsq = sqi + sp - 2.f * dp;
            dsq = dsq > 0.f ? dsq : 0.f;
            // reference's zero-mask only affects exact-zero entries (diagonal),
            // which validity excludes -> plain sqrt exact for used entries.
            drow[j] = (dsq == 0.f) ? 0.f : sqrtf(dsq);
        }
    }
    __syncthreads();

    // compact positives (~8 per anchor -> negligible atomics)
    for (int j = tid; j < NPTS; j += 256) {
        if (lab[j] == li && j != i) {
            int p = atomicAdd(&npos_sh, 1);
            posv[p] = drow[j] + MARGIN;
        }
    }
    __syncthreads();
    const int npos = npos_sh;

    // pair loop: predicated scan over all k (nneg/NPTS ~ 98% useful lanes)
    float lsum = 0.f;
    int   lcnt = 0;
    for (int p = 0; p < npos; ++p) {
        const float a = posv[p];
        for (int k = tid; k < NPTS; k += 256) {
            if (lab[k] != li) {
                float v = a - drow[k];       // d_ij - d_ik + margin
                if (v > 0.f) {
                    lsum += v;
                    lcnt += (v > CNT_EPS) ? 1 : 0;
                }
            }
        }
    }

    red_s[tid] = lsum;
    red_c[tid] = lcnt;
    __syncthreads();
    for (int s = 128; s > 0; s >>= 1) {
        if (tid < s) {
            red_s[tid] += red_s[tid + s];
            red_c[tid] += red_c[tid + s];
        }
        __syncthreads();
    }

    if (tid == 0) {
        unsigned long long q =
            (unsigned long long)((double)red_s[0] * FIXSCALE + 0.5);
        atomicAdd(&acc->sum, q);
        atomicAdd(&acc->cnt, (unsigned int)red_c[0]);
        __threadfence();                      // publish before ticket
        unsigned int t = atomicAdd(&acc->ticket, 1u);
        if (t == (unsigned int)(nblocks - 1)) {
            unsigned long long s = atomicAdd(&acc->sum, 0ULL);
            unsigned int       cc = atomicAdd(&acc->cnt, 0u);
            out[0] = (float)(((double)s / FIXSCALE) / (double)cc);
        }
    }
}

extern "C" void kernel_launch(void* const* d_in, const int* in_sizes, int n_in,
                              void* d_out, int out_size, void* d_ws, size_t ws_size,
                              hipStream_t stream) {
    const float* x      = (const float*)d_in[0];   // [512,128] fp32
    const int*   labels = (const int*)d_in[1];     // [512] int32
    float*       out    = (float*)d_out;           // scalar fp32
    Accum*       acc    = (Accum*)d_ws;

    hipMemsetAsync(acc, 0, sizeof(Accum), stream); // replay-safe re-zero
    triplet_fused_kernel<<<NPTS, 256, 0, stream>>>(x, labels, out, acc, NPTS);
}

// Round 4
// 19.180 us; speedup vs baseline: 2.4108x; 1.9332x over previous
//
#include <hip/hip_runtime.h>

#define NPTS 512
#define DIM  128
#define MARGIN 0.5f
#define CNT_EPS 1e-8f

__device__ __forceinline__ float dot4(float4 a, float4 b) {
    return a.x * b.x + a.y * b.y + a.z * b.z + a.w * b.w;
}

// ---------------------------------------------------------------------------
// One block (256 thr = 4 waves) per anchor i.
// Distance phase: 4 lanes per row j, 16 rows per wave per pass, 8 passes
// (coalesced: each wave-level load touches 16 fully-used 64B segments;
//  anchor row xi held in registers, 8 x float4 per lane).
// Then: distance row in LDS, compact ~8 positives, predicated pair loop,
// block tree-reduce, PLAIN global store of (psum, pcnt). No fences/atomics.
// ---------------------------------------------------------------------------
__global__ __launch_bounds__(256)
void triplet_row_kernel(const float* __restrict__ x,
                        const int* __restrict__ labels,
                        float* __restrict__ psum,
                        int* __restrict__ pcnt) {
    __shared__ float drow[NPTS];   // distance row d[i][*]
    __shared__ int   lab[NPTS];
    __shared__ float posv[NPTS];
    __shared__ int   npos_sh;
    __shared__ float red_s[256];
    __shared__ int   red_c[256];

    const int i   = blockIdx.x;
    const int tid = threadIdx.x;
    const int w   = tid >> 6;      // wave 0..3
    const int l   = tid & 63;      // lane
    const int g   = l >> 2;        // row-group 0..15 within wave
    const int c   = l & 3;         // column slot 0..3 within group

    lab[tid]       = labels[tid];
    lab[tid + 256] = labels[tid + 256];
    if (tid == 0) npos_sh = 0;
    const int li = labels[i];

    // anchor row fragment in registers: columns c+4*it (it=0..7)
    const float4* xi4 = (const float4*)(x + i * DIM);
    float4 xf[8];
#pragma unroll
    for (int it = 0; it < 8; ++it) xf[it] = xi4[c + 4 * it];

    // sqi = ||xi||^2 : per-lane partial, 4-lane butterfly
    float sqi = 0.f;
#pragma unroll
    for (int it = 0; it < 8; ++it) sqi += dot4(xf[it], xf[it]);
    sqi += __shfl_xor(sqi, 1, 64);
    sqi += __shfl_xor(sqi, 2, 64);

    // distance rows: wave w, pass p covers rows p*64 + w*16 + g
#pragma unroll 2
    for (int pass = 0; pass < 8; ++pass) {
        const int j = pass * 64 + w * 16 + g;
        const float4* xj4 = (const float4*)(x + j * DIM);
        float dp = 0.f, sp = 0.f;
#pragma unroll
        for (int it = 0; it < 8; ++it) {
            float4 b = xj4[c + 4 * it];
            dp += dot4(b, xf[it]);
            sp += dot4(b, b);
        }
        dp += __shfl_xor(dp, 1, 64);
        dp += __shfl_xor(dp, 2, 64);
        sp += __shfl_xor(sp, 1, 64);
        sp += __shfl_xor(sp, 2, 64);
        if (c == 0) {
            float dsq = sqi + sp - 2.f * dp;
            dsq = dsq > 0.f ? dsq : 0.f;
            // reference's zero-mask only affects exact-zero entries (the
            // diagonal), excluded by validity -> plain sqrt exact here.
            drow[j] = (dsq == 0.f) ? 0.f : sqrtf(dsq);
        }
    }
    __syncthreads();

    // compact positives (~8 per anchor -> negligible atomics)
    for (int j = tid; j < NPTS; j += 256) {
        if (lab[j] == li && j != i) {
            int p = atomicAdd(&npos_sh, 1);
            posv[p] = drow[j] + MARGIN;
        }
    }
    __syncthreads();
    const int npos = npos_sh;

    // pair loop: predicated scan over all k (~98% useful lanes)
    float lsum = 0.f;
    int   lcnt = 0;
    for (int p = 0; p < npos; ++p) {
        const float a = posv[p];
        for (int k = tid; k < NPTS; k += 256) {
            if (lab[k] != li) {
                float v = a - drow[k];       // d_ij - d_ik + margin
                if (v > 0.f) {
                    lsum += v;
                    lcnt += (v > CNT_EPS) ? 1 : 0;
                }
            }
        }
    }

    red_s[tid] = lsum;
    red_c[tid] = lcnt;
    __syncthreads();
    for (int s = 128; s > 0; s >>= 1) {
        if (tid < s) {
            red_s[tid] += red_s[tid + s];
            red_c[tid] += red_c[tid + s];
        }
        __syncthreads();
    }
    if (tid == 0) {
        psum[i] = red_s[0];     // plain stores; kernel-boundary coherence
        pcnt[i] = red_c[0];     // is runtime-managed (one flush, not 512)
    }
}

// ---------------------------------------------------------------------------
// 1-block finalize: deterministic fixed-order reduce of 512 partials.
// ---------------------------------------------------------------------------
__global__ void finalize_kernel(const float* __restrict__ psum,
                                const int* __restrict__ pcnt,
                                float* __restrict__ out) {
    __shared__ float rs[256];
    __shared__ int   rc[256];
    const int tid = threadIdx.x;
    rs[tid] = psum[tid] + psum[tid + 256];
    rc[tid] = pcnt[tid] + pcnt[tid + 256];
    __syncthreads();
    for (int s = 128; s > 0; s >>= 1) {
        if (tid < s) {
            rs[tid] += rs[tid + s];
            rc[tid] += rc[tid + s];
        }
        __syncthreads();
    }
    if (tid == 0) out[0] = rs[0] / (float)rc[0];
}

extern "C" void kernel_launch(void* const* d_in, const int* in_sizes, int n_in,
                              void* d_out, int out_size, void* d_ws, size_t ws_size,
                              hipStream_t stream) {
    const float* x      = (const float*)d_in[0];   // [512,128] fp32
    const int*   labels = (const int*)d_in[1];     // [512] int32
    float*       out    = (float*)d_out;           // scalar fp32

    float* psum = (float*)d_ws;          // 512 floats (fully overwritten)
    int*   pcnt = (int*)(psum + NPTS);   // 512 ints  (fully overwritten)

    triplet_row_kernel<<<NPTS, 256, 0, stream>>>(x, labels, psum, pcnt);
    finalize_kernel<<<1, 256, 0, stream>>>(psum, pcnt, out);
}

// Round 5
// 16.390 us; speedup vs baseline: 2.8212x; 1.1702x over previous
//
#include <hip/hip_runtime.h>

#define NPTS 512
#define DIM  128
#define MARGIN 0.5f
#define CNT_EPS 1e-8f

__device__ __forceinline__ float dot4(float4 a, float4 b) {
    return a.x * b.x + a.y * b.y + a.z * b.z + a.w * b.w;
}

// ---------------------------------------------------------------------------
// One block (512 thr = 8 waves) per anchor i; grid 512 -> 2 blocks/CU =
// 4 waves/SIMD (max at VGPR=128) for L2-latency hiding.
// Distance phase: 4 lanes per row j, 16 rows per wave per pass, 4 passes.
// Then: one thread per row -> single-step positive compaction and pair loop;
// per-wave shuffle reduce + 8-partial combine (2 syncs total in the tail).
// ---------------------------------------------------------------------------
__global__ __launch_bounds__(512, 4)
void triplet_row_kernel(const float* __restrict__ x,
                        const int* __restrict__ labels,
                        float* __restrict__ psum,
                        int* __restrict__ pcnt) {
    __shared__ float drow[NPTS];   // distance row d[i][*]
    __shared__ int   lab[NPTS];
    __shared__ float posv[NPTS];
    __shared__ int   npos_sh;
    __shared__ float wsum[8];
    __shared__ int   wcnt[8];

    const int i   = blockIdx.x;
    const int tid = threadIdx.x;   // 0..511
    const int w   = tid >> 6;      // wave 0..7
    const int l   = tid & 63;      // lane
    const int g   = l >> 2;        // row-group 0..15 within wave
    const int c   = l & 3;         // column slot 0..3 within group

    lab[tid] = labels[tid];
    if (tid == 0) npos_sh = 0;
    const int li = labels[i];

    // anchor row fragment in registers: columns c+4*it (it=0..7)
    const float4* xi4 = (const float4*)(x + i * DIM);
    float4 xf[8];
#pragma unroll
    for (int it = 0; it < 8; ++it) xf[it] = xi4[c + 4 * it];

    // sqi = ||xi||^2 : per-lane partial, 4-lane butterfly
    float sqi = 0.f;
#pragma unroll
    for (int it = 0; it < 8; ++it) sqi += dot4(xf[it], xf[it]);
    sqi += __shfl_xor(sqi, 1, 64);
    sqi += __shfl_xor(sqi, 2, 64);

    // distance rows: pass p covers rows p*128 + w*16 + g
#pragma unroll 2
    for (int pass = 0; pass < 4; ++pass) {
        const int j = pass * 128 + w * 16 + g;
        const float4* xj4 = (const float4*)(x + j * DIM);
        float dp = 0.f, sp = 0.f;
#pragma unroll
        for (int it = 0; it < 8; ++it) {
            float4 b = xj4[c + 4 * it];
            dp += dot4(b, xf[it]);
            sp += dot4(b, b);
        }
        dp += __shfl_xor(dp, 1, 64);
        dp += __shfl_xor(dp, 2, 64);
        sp += __shfl_xor(sp, 1, 64);
        sp += __shfl_xor(sp, 2, 64);
        if (c == 0) {
            float dsq = sqi + sp - 2.f * dp;
            dsq = dsq > 0.f ? dsq : 0.f;
            // reference's zero-mask only affects exact-zero entries (the
            // diagonal), excluded by validity -> plain sqrt exact here.
            drow[j] = (dsq == 0.f) ? 0.f : sqrtf(dsq);
        }
    }
    __syncthreads();

    // compact positives: one thread per row (~8 atomics per block)
    if (lab[tid] == li && tid != i) {
        int p = atomicAdd(&npos_sh, 1);
        posv[p] = drow[tid] + MARGIN;
    }
    __syncthreads();
    const int npos = npos_sh;

    // pair loop: this thread owns k = tid
    const bool isneg = (lab[tid] != li);
    const float dk   = drow[tid];
    float lsum = 0.f;
    int   lcnt = 0;
    for (int p = 0; p < npos; ++p) {
        float v = posv[p] - dk;          // d_ij - d_ik + margin
        if (isneg && v > 0.f) {
            lsum += v;
            lcnt += (v > CNT_EPS) ? 1 : 0;
        }
    }

    // per-wave shuffle reduce, then 8-partial combine
#pragma unroll
    for (int off = 1; off < 64; off <<= 1) {
        lsum += __shfl_xor(lsum, off, 64);
        lcnt += __shfl_xor(lcnt, off, 64);
    }
    if (l == 0) { wsum[w] = lsum; wcnt[w] = lcnt; }
    __syncthreads();
    if (tid == 0) {
        float s = 0.f;
        int   cc = 0;
#pragma unroll
        for (int q = 0; q < 8; ++q) { s += wsum[q]; cc += wcnt[q]; }
        psum[i] = s;                 // plain stores; kernel-boundary
        pcnt[i] = cc;                // coherence is runtime-managed
    }
}

// ---------------------------------------------------------------------------
// Finalize: ONE wave, vectorized loads, shuffle reduce, no LDS/syncthreads.
// ---------------------------------------------------------------------------
__global__ void finalize_kernel(const float4* __restrict__ psum4,
                                const int4* __restrict__ pcnt4,
                                float* __restrict__ out) {
    const int t = threadIdx.x;       // 0..63
    float4 a = psum4[2 * t];
    float4 b = psum4[2 * t + 1];
    int4   ca = pcnt4[2 * t];
    int4   cb = pcnt4[2 * t + 1];
    float s = (a.x + a.y + a.z + a.w) + (b.x + b.y + b.z + b.w);
    int   cc = (ca.x + ca.y + ca.z + ca.w) + (cb.x + cb.y + cb.z + cb.w);
#pragma unroll
    for (int off = 1; off < 64; off <<= 1) {
        s  += __shfl_xor(s, off, 64);
        cc += __shfl_xor(cc, off, 64);
    }
    if (t == 0) out[0] = s / (float)cc;
}

extern "C" void kernel_launch(void* const* d_in, const int* in_sizes, int n_in,
                              void* d_out, int out_size, void* d_ws, size_t ws_size,
                              hipStream_t stream) {
    const float* x      = (const float*)d_in[0];   // [512,128] fp32
    const int*   labels = (const int*)d_in[1];     // [512] int32
    float*       out    = (float*)d_out;           // scalar fp32

    float* psum = (float*)d_ws;          // 512 floats (fully overwritten)
    int*   pcnt = (int*)(psum + NPTS);   // 512 ints  (fully overwritten)

    triplet_row_kernel<<<NPTS, 512, 0, stream>>>(x, labels, psum, pcnt);
    finalize_kernel<<<1, 64, 0, stream>>>((const float4*)psum,
                                          (const int4*)pcnt, out);
}